// Round 8
// baseline (137.547 us; speedup 1.0000x reference)
//
#include <hip/hip_runtime.h>

// SensorAutoEncoder: 10-layer MLP over 1M rows of 43 floats, fused persistent
// kernel. fp16 MFMA (16x16x32) + fp32 accumulate. R8 = R7 (register-resident
// layer chain, k-permutation F folded into weight staging, global_load_lds
// x-staging, <=64 VGPR) + three issue-count cuts:
//   (a) acc init via first-MFMA with shared zero C block (no v_mov burst)
//   (b) x DMA'd into [32][48-float] aligned LDS rows (per-lane src remap)
//       -> layer-0 frags via 8x ds_read_b128 instead of ~32 scalar reads
//   (c) layer-9 stores: one byte-base + compile-time immediate offsets
// B slot (c,g,j): c==0 -> F = 16*(j>>2) + 4g + (j&3)
//                 c==1, j<4 -> F = 32 + 4g + j ; else zero pad

typedef __fp16 pk16x2 __attribute__((ext_vector_type(2)));   // cvt_pkrtz type
typedef _Float16 f16x8 __attribute__((ext_vector_type(8)));
typedef float f32x4 __attribute__((ext_vector_type(4)));
typedef unsigned u32x4 __attribute__((ext_vector_type(4)));

#define TPB 1024
#define NBLK 256
#define ITERS 8
#define NROWS 1048576
#define NCOL 43
#define ROWB 172u                        // bytes per x row (43 f32)
#define XBYTES ((size_t)NROWS * ROWB)    // 180,355,072
#define WSTRIDE 72                       // halfwords per W^T row (144 B)
#define SLOT_ROWS 44
#define WSLOT (SLOT_ROWS * WSTRIDE)      // 3168 halfwords per layer slot
#define W_BYTES (10 * WSLOT * 2)         // 63360 B
#define XBUF_BYTES 6144                  // 32 rows * 48 f32 = 6144 exactly
#define X_BASE W_BYTES
// +64 pad: last wave's layer-0 c1 reads for g=3 run 32B past its buffer
#define SMEM_BYTES (X_BASE + 16 * XBUF_BYTES + 64)  // 161728 <= 163840

__device__ __forceinline__ float fast_tanh(float x) {
  // tanh(x) = 1 - 2/(1 + e^{2x});  e^{2x} = 2^{x * 2*log2(e)}
  float t = __builtin_amdgcn_exp2f(x * 2.8853900817779268f);
  float r = __builtin_amdgcn_rcpf(t + 1.0f);
  return __builtin_fmaf(-2.0f, r, 1.0f);
}

__device__ __forceinline__ unsigned pk2(float a, float b) {
  pk16x2 h = __builtin_amdgcn_cvt_pkrtz(a, b);
  return __builtin_bit_cast(unsigned, h);
}

struct FragsV { f16x8 s0c0, s0c1, s1c0, s1c1; };

// One layer, self-contained: MFMA vs LDS weights (first chunk uses zero C),
// epilogue (tanh + bias-column 1.0 forcing), pack straight into next B-frags.
template <int NT, int KC, bool DOTANH, int NLOUT, int KCN>
__device__ __forceinline__ FragsV layer_fwd(const _Float16* __restrict__ Wl,
                                            FragsV Bi, f32x4 Z, int g, int lr) {
  f16x8 Bv[2][2];
  Bv[0][0] = Bi.s0c0; Bv[0][1] = Bi.s0c1;
  Bv[1][0] = Bi.s1c0; Bv[1][1] = Bi.s1c1;

  f32x4 acc[3][2];
#pragma unroll
  for (int t = 0; t < NT; ++t) {        // c = 0, C := zero block
    f16x8 A = *(const f16x8*)(Wl + (16 * t + lr) * WSTRIDE + 8 * g);
#pragma unroll
    for (int s = 0; s < 2; ++s)
      acc[t][s] = __builtin_amdgcn_mfma_f32_16x16x32_f16(A, Bv[s][0], Z,
                                                         0, 0, 0);
  }
#pragma unroll
  for (int c = 1; c < KC; ++c)
#pragma unroll
    for (int t = 0; t < NT; ++t) {
      f16x8 A = *(const f16x8*)(Wl + (16 * t + lr) * WSTRIDE + 8 * g + 32 * c);
#pragma unroll
      for (int s = 0; s < 2; ++s)
        acc[t][s] = __builtin_amdgcn_mfma_f32_16x16x32_f16(A, Bv[s][c],
                                                           acc[t][s], 0, 0, 0);
    }

  f16x8 oc0[2], oc1[2];
#pragma unroll
  for (int s = 0; s < 2; ++s) {
    unsigned pk[3][2];
#pragma unroll
    for (int t = 0; t < NT; ++t) {
      float v[4];
#pragma unroll
      for (int r = 0; r < 4; ++r) {
        float u = acc[t][s][r];
        if (DOTANH) u = fast_tanh(u);
        if (t == (NLOUT >> 4)) {                 // bias-mult column -> 1.0
          int col = 16 * t + 4 * g + r;
          u = (col == NLOUT) ? 1.0f : u;
        }
        v[r] = u;
      }
      pk[t][0] = pk2(v[0], v[1]);
      pk[t][1] = pk2(v[2], v[3]);
    }
    u32x4 d0 = {pk[0][0], pk[0][1], pk[1][0], pk[1][1]};
    oc0[s] = __builtin_bit_cast(f16x8, d0);
    if (KCN == 2) {
      u32x4 d1 = {pk[NT - 1][0], pk[NT - 1][1], 0u, 0u};
      oc1[s] = __builtin_bit_cast(f16x8, d1);
    } else {
      oc1[s] = oc0[s];   // unused by a KC=1 consumer
    }
  }
  FragsV O;
  O.s0c0 = oc0[0]; O.s0c1 = oc1[0];
  O.s1c0 = oc0[1]; O.s1c1 = oc1[1];
  return O;
}

extern "C" __global__ void __launch_bounds__(TPB)
ae_kernel(const float* __restrict__ x,
          const float* __restrict__ W0, const float* __restrict__ B0,
          const float* __restrict__ W1, const float* __restrict__ B1,
          const float* __restrict__ W2, const float* __restrict__ B2,
          const float* __restrict__ W3, const float* __restrict__ B3,
          const float* __restrict__ W4, const float* __restrict__ B4,
          const float* __restrict__ W5, const float* __restrict__ B5,
          const float* __restrict__ W6, const float* __restrict__ B6,
          const float* __restrict__ W7, const float* __restrict__ B7,
          const float* __restrict__ W8, const float* __restrict__ B8,
          const float* __restrict__ W9, const float* __restrict__ B9,
          float* __restrict__ out) {
  extern __shared__ char smem[];
  _Float16* lw = (_Float16*)smem;

  const int tid = threadIdx.x;
  const int wave = tid >> 6;
  const int lane = tid & 63;
  const int g = lane >> 4;
  const int lr = lane & 15;

  // ---- stage weights as fp16 W^T (k-permutation F for layers 1..9), bias
  //      at the slot mapping to k==KL; 44 rows per slot ----
  {
    const float* Wp[10] = {W0, W1, W2, W3, W4, W5, W6, W7, W8, W9};
    const float* Bp[10] = {B0, B1, B2, B3, B4, B5, B6, B7, B8, B9};
    const int KLs[10] = {43, 43, 43, 43, 43, 21, 43, 43, 43, 43};
    const int NLs[10] = {43, 43, 43, 43, 21, 43, 43, 43, 43, 43};
#pragma unroll
    for (int L = 0; L < 10; ++L) {
      const float* Wl = Wp[L];
      const float* Bl = Bp[L];
      const int KL = KLs[L], NL = NLs[L];
      for (int idx = tid; idx < SLOT_ROWS * 64; idx += TPB) {
        int n = idx >> 6, kp = idx & 63;
        float v = 0.0f;
        if (n < NL) {
          int c = kp >> 5, g2 = (kp >> 3) & 3, j = kp & 7;
          int F;
          if (L == 0) F = kp;                               // natural
          else if (c == 0) F = 16 * (j >> 2) + 4 * g2 + (j & 3);
          else if (j < 4)  F = 32 + 4 * g2 + j;             // t=2 half
          else             F = 63;                          // zero pad slot
          if (F < KL) v = Wl[F * NL + n];                   // W^T: W[F][n]
          else if (F == KL) v = Bl[n];                      // bias row
        }
        lw[L * WSLOT + n * WSTRIDE + kp] = (_Float16)v;
      }
    }
  }

  // per-lane DMA source offsets: LDS quad u=64i+lane holds x bytes
  // [row*172 + q*16) with row=u/12, q=u%12  (LDS layout = [32 rows][48 f32])
  unsigned dmaoff[6];
#pragma unroll
  for (int i = 0; i < 6; ++i) {
    unsigned u = 64u * i + (unsigned)lane;
    dmaoff[i] = (u / 12u) * ROWB + (u % 12u) * 16u;
  }

  __syncthreads();  // weights ready; only barrier in the kernel

  const char* xc = (const char*)x;
  const char* xlim = xc + (XBYTES - 16);
  const unsigned blockbase = (unsigned)blockIdx.x * (ITERS * 512) + wave * 32;
  float* xb = (float*)(smem + X_BASE + wave * XBUF_BYTES);
  const f32x4 Z = {0.f, 0.f, 0.f, 0.f};   // shared MFMA C-init block

  // issue DMA of tile 0
  {
    const char* base = xc + blockbase * ROWB;
#pragma unroll
    for (int i = 0; i < 6; ++i) {
      const char* src = base + dmaoff[i];
      src = (src > xlim) ? xlim : src;
      __builtin_amdgcn_global_load_lds(
          (const __attribute__((address_space(1))) void*)src,
          (__attribute__((address_space(3))) void*)((char*)xb + i * 1024),
          16, 0, 0);
    }
  }

#pragma unroll 1
  for (int it = 0; it < ITERS; ++it) {
    const unsigned row0 = blockbase + (unsigned)it * 512u;

    asm volatile("s_waitcnt vmcnt(0)" ::: "memory");  // x tile landed in LDS

    // ---- layer-0 B-frags from aligned LDS rows; slot k==43 := 1.0 ----
    FragsV B;
#pragma unroll
    for (int s = 0; s < 2; ++s) {
      const float* xr = xb + (16 * s + lr) * 48;
      f32x4 q0 = *(const f32x4*)(xr + 8 * g);
      f32x4 q1 = *(const f32x4*)(xr + 8 * g + 4);
      f32x4 q2 = *(const f32x4*)(xr + 32 + 8 * g);   // g>=2 bleeds into next
      f32x4 q3 = *(const f32x4*)(xr + 36 + 8 * g);   // row: junk, annihilated
      float e3 = (g == 1) ? 1.0f : q2[3];            // k==43 bias multiplier
      u32x4 d0 = {pk2(q0[0], q0[1]), pk2(q0[2], q0[3]),
                  pk2(q1[0], q1[1]), pk2(q1[2], q1[3])};
      u32x4 d1 = {pk2(q2[0], q2[1]), pk2(q2[2], e3),
                  pk2(q3[0], q3[1]), pk2(q3[2], q3[3])};
      if (s == 0) { B.s0c0 = __builtin_bit_cast(f16x8, d0);
                    B.s0c1 = __builtin_bit_cast(f16x8, d1); }
      else        { B.s1c0 = __builtin_bit_cast(f16x8, d0);
                    B.s1c1 = __builtin_bit_cast(f16x8, d1); }
    }

    // frag reads complete -> safe to overwrite the buffer with next tile
    asm volatile("s_waitcnt lgkmcnt(0)" ::: "memory");
    if (it + 1 < ITERS) {
      const char* base = xc + (row0 + 512u) * ROWB;
#pragma unroll
      for (int i = 0; i < 6; ++i) {
        const char* src = base + dmaoff[i];
        src = (src > xlim) ? xlim : src;
        __builtin_amdgcn_global_load_lds(
            (const __attribute__((address_space(1))) void*)src,
            (__attribute__((address_space(3))) void*)((char*)xb + i * 1024),
            16, 0, 0);
      }
    }

    // ---- layers 0..8, hidden state entirely in registers ----
    B = layer_fwd<3, 2, true, 43, 2>(lw + 0 * WSLOT, B, Z, g, lr);
    B = layer_fwd<3, 2, true, 43, 2>(lw + 1 * WSLOT, B, Z, g, lr);
    B = layer_fwd<3, 2, true, 43, 2>(lw + 2 * WSLOT, B, Z, g, lr);
    B = layer_fwd<3, 2, true, 43, 2>(lw + 3 * WSLOT, B, Z, g, lr);
    B = layer_fwd<2, 2, false, 21, 1>(lw + 4 * WSLOT, B, Z, g, lr);
    B = layer_fwd<3, 1, true, 43, 2>(lw + 5 * WSLOT, B, Z, g, lr);
    B = layer_fwd<3, 2, true, 43, 2>(lw + 6 * WSLOT, B, Z, g, lr);
    B = layer_fwd<3, 2, true, 43, 2>(lw + 7 * WSLOT, B, Z, g, lr);
    B = layer_fwd<3, 2, true, 43, 2>(lw + 8 * WSLOT, B, Z, g, lr);

    // ---- layer 9: linear, store fp32 via base + immediate offsets ----
    {
      f16x8 Bv[2][2];
      Bv[0][0] = B.s0c0; Bv[0][1] = B.s0c1;
      Bv[1][0] = B.s1c0; Bv[1][1] = B.s1c1;
      f32x4 a9[3][2];
#pragma unroll
      for (int t = 0; t < 3; ++t) {
        f16x8 A = *(const f16x8*)(lw + 9 * WSLOT + (16 * t + lr) * WSTRIDE +
                                  8 * g);
#pragma unroll
        for (int s = 0; s < 2; ++s)
          a9[t][s] = __builtin_amdgcn_mfma_f32_16x16x32_f16(A, Bv[s][0], Z,
                                                            0, 0, 0);
      }
#pragma unroll
      for (int t = 0; t < 3; ++t) {
        f16x8 A = *(const f16x8*)(lw + 9 * WSLOT + (16 * t + lr) * WSTRIDE +
                                  8 * g + 32);
#pragma unroll
        for (int s = 0; s < 2; ++s)
          a9[t][s] = __builtin_amdgcn_mfma_f32_16x16x32_f16(A, Bv[s][1],
                                                            a9[t][s], 0, 0, 0);
      }
      char* ob = (char*)out + ((size_t)(row0 + lr) * ROWB + 16u * g);
#pragma unroll
      for (int t = 0; t < 3; ++t)
#pragma unroll
        for (int s = 0; s < 2; ++s)
#pragma unroll
          for (int r = 0; r < 4; ++r) {
            // col = 16t + 4g + r < 43; t<2 always in range
            if (t < 2 || 4 * g + r < 11)
              *(float*)(ob + 2752 * s + 64 * t + 4 * r) = a9[t][s][r];
          }
    }
  }
}

extern "C" void kernel_launch(void* const* d_in, const int* in_sizes, int n_in,
                              void* d_out, int out_size, void* d_ws,
                              size_t ws_size, hipStream_t stream) {
  const float* x = (const float*)d_in[0];
  const float* W[10];
  const float* B[10];
  for (int i = 0; i < 10; ++i) {
    W[i] = (const float*)d_in[1 + 2 * i];
    B[i] = (const float*)d_in[2 + 2 * i];
  }
  (void)hipFuncSetAttribute(reinterpret_cast<const void*>(ae_kernel),
                            hipFuncAttributeMaxDynamicSharedMemorySize,
                            SMEM_BYTES);
  ae_kernel<<<dim3(NBLK), dim3(TPB), SMEM_BYTES, stream>>>(
      x, W[0], B[0], W[1], B[1], W[2], B[2], W[3], B[3], W[4], B[4],
      W[5], B[5], W[6], B[6], W[7], B[7], W[8], B[8], W[9], B[9],
      (float*)d_out);
}

// Round 9
// 135.880 us; speedup vs baseline: 1.0123x; 1.0123x over previous
//
#include <hip/hip_runtime.h>

// SensorAutoEncoder: 10-layer MLP over 1M rows of 43 floats, fused persistent
// kernel. fp16 MFMA (16x16x32) + fp32 accumulate. R9 = R8 (register-resident
// layer chain, k-permutation F folded into weight staging, global_load_lds
// x-staging) + latency attack:
//   (a) x LDS rows at 176 B stride (11 aligned quads; 2-way banks = free,
//       vs 192 B stride's 8-way conflict) — DMA src = 172r + 16q, contiguous
//   (b) A-fragments software-pipelined one layer ahead into registers
//       (named-struct A6, static member indexing; ds_reads issue before the
//       previous layer's MFMA+tanh epilogue -> LDS latency hidden)
// B slot (c,g,j): c==0 -> F = 16*(j>>2) + 4g + (j&3)
//                 c==1, j<4 -> F = 32 + 4g + j ; else zero pad

typedef __fp16 pk16x2 __attribute__((ext_vector_type(2)));   // cvt_pkrtz type
typedef _Float16 f16x8 __attribute__((ext_vector_type(8)));
typedef float f32x4 __attribute__((ext_vector_type(4)));
typedef unsigned u32x4 __attribute__((ext_vector_type(4)));

#define TPB 1024
#define NBLK 256
#define ITERS 8
#define NROWS 1048576
#define NCOL 43
#define ROWB 172u                        // bytes per x / out row (43 f32)
#define XBYTES ((size_t)NROWS * ROWB)    // 180,355,072
#define WSTRIDE 72                       // halfwords per W^T row (144 B)
#define SLOT_ROWS 44
#define WSLOT (SLOT_ROWS * WSTRIDE)      // 3168 halfwords per layer slot
#define W_BYTES (10 * WSLOT * 2)         // 63360 B
#define W_PAD 640                        // layer-9 A-read overhang (rows 44..47)
#define XROWF 44                         // floats per x LDS row (176 B)
#define XBUF_BYTES 6144                  // 32*176 = 5632 + 512 pad
#define X_BASE (W_BYTES + W_PAD)
#define SMEM_BYTES (X_BASE + 16 * XBUF_BYTES)  // 162304 <= 163840

__device__ __forceinline__ float fast_tanh(float x) {
  // tanh(x) = 1 - 2/(1 + e^{2x});  e^{2x} = 2^{x * 2*log2(e)}
  float t = __builtin_amdgcn_exp2f(x * 2.8853900817779268f);
  float r = __builtin_amdgcn_rcpf(t + 1.0f);
  return __builtin_fmaf(-2.0f, r, 1.0f);
}

__device__ __forceinline__ unsigned pk2(float a, float b) {
  pk16x2 h = __builtin_amdgcn_cvt_pkrtz(a, b);
  return __builtin_bit_cast(unsigned, h);
}

struct FragsV { f16x8 s0c0, s0c1, s1c0, s1c1; };
struct A6 { f16x8 m0, m1, m2, m3, m4, m5; };   // [c*3+t], NT/KC-guarded use

template <int NT, int KC>
__device__ __forceinline__ A6 load_A(const _Float16* __restrict__ Wl,
                                     int g, int lr) {
  A6 a;
  const _Float16* p = Wl + lr * WSTRIDE + 8 * g;
  a.m0 = *(const f16x8*)(p);
  if constexpr (NT > 1) a.m1 = *(const f16x8*)(p + 16 * WSTRIDE);
  if constexpr (NT > 2) a.m2 = *(const f16x8*)(p + 32 * WSTRIDE);
  if constexpr (KC > 1) {
    a.m3 = *(const f16x8*)(p + 32);
    if constexpr (NT > 1) a.m4 = *(const f16x8*)(p + 16 * WSTRIDE + 32);
    if constexpr (NT > 2) a.m5 = *(const f16x8*)(p + 32 * WSTRIDE + 32);
  }
  return a;
}

// One layer from preloaded A-frags: MFMA (first K-chunk uses zero C),
// epilogue (tanh + bias-column 1.0 forcing), pack into next B-frags.
template <int NT, int KC, bool DOTANH, int NLOUT, int KCN>
__device__ __forceinline__ FragsV layer_fwd(A6 a, FragsV Bi, f32x4 Z, int g) {
  f16x8 Bv0[2] = {Bi.s0c0, Bi.s1c0};
  f16x8 Bv1[2] = {Bi.s0c1, Bi.s1c1};

  f32x4 acc[3][2];
#pragma unroll
  for (int s = 0; s < 2; ++s) {
    acc[0][s] = __builtin_amdgcn_mfma_f32_16x16x32_f16(a.m0, Bv0[s], Z, 0, 0, 0);
    if constexpr (NT > 1)
      acc[1][s] = __builtin_amdgcn_mfma_f32_16x16x32_f16(a.m1, Bv0[s], Z, 0, 0, 0);
    if constexpr (NT > 2)
      acc[2][s] = __builtin_amdgcn_mfma_f32_16x16x32_f16(a.m2, Bv0[s], Z, 0, 0, 0);
  }
  if constexpr (KC > 1) {
#pragma unroll
    for (int s = 0; s < 2; ++s) {
      acc[0][s] = __builtin_amdgcn_mfma_f32_16x16x32_f16(a.m3, Bv1[s],
                                                         acc[0][s], 0, 0, 0);
      if constexpr (NT > 1)
        acc[1][s] = __builtin_amdgcn_mfma_f32_16x16x32_f16(a.m4, Bv1[s],
                                                           acc[1][s], 0, 0, 0);
      if constexpr (NT > 2)
        acc[2][s] = __builtin_amdgcn_mfma_f32_16x16x32_f16(a.m5, Bv1[s],
                                                           acc[2][s], 0, 0, 0);
    }
  }

  f16x8 oc0[2], oc1[2];
#pragma unroll
  for (int s = 0; s < 2; ++s) {
    unsigned pk[3][2];
#pragma unroll
    for (int t = 0; t < NT; ++t) {
      float v[4];
#pragma unroll
      for (int r = 0; r < 4; ++r) {
        float u = acc[t][s][r];
        if (DOTANH) u = fast_tanh(u);
        if (t == (NLOUT >> 4)) {                 // bias-mult column -> 1.0
          int col = 16 * t + 4 * g + r;
          u = (col == NLOUT) ? 1.0f : u;
        }
        v[r] = u;
      }
      pk[t][0] = pk2(v[0], v[1]);
      pk[t][1] = pk2(v[2], v[3]);
    }
    u32x4 d0 = {pk[0][0], pk[0][1], pk[1][0], pk[1][1]};
    oc0[s] = __builtin_bit_cast(f16x8, d0);
    if (KCN == 2) {
      u32x4 d1 = {pk[NT - 1][0], pk[NT - 1][1], 0u, 0u};
      oc1[s] = __builtin_bit_cast(f16x8, d1);
    } else {
      oc1[s] = oc0[s];   // unused by a KC=1 consumer
    }
  }
  FragsV O;
  O.s0c0 = oc0[0]; O.s0c1 = oc1[0];
  O.s1c0 = oc0[1]; O.s1c1 = oc1[1];
  return O;
}

extern "C" __global__ void __launch_bounds__(TPB, 4)
ae_kernel(const float* __restrict__ x,
          const float* __restrict__ W0, const float* __restrict__ B0,
          const float* __restrict__ W1, const float* __restrict__ B1,
          const float* __restrict__ W2, const float* __restrict__ B2,
          const float* __restrict__ W3, const float* __restrict__ B3,
          const float* __restrict__ W4, const float* __restrict__ B4,
          const float* __restrict__ W5, const float* __restrict__ B5,
          const float* __restrict__ W6, const float* __restrict__ B6,
          const float* __restrict__ W7, const float* __restrict__ B7,
          const float* __restrict__ W8, const float* __restrict__ B8,
          const float* __restrict__ W9, const float* __restrict__ B9,
          float* __restrict__ out) {
  extern __shared__ char smem[];
  _Float16* lw = (_Float16*)smem;

  const int tid = threadIdx.x;
  const int wave = tid >> 6;
  const int lane = tid & 63;
  const int g = lane >> 4;
  const int lr = lane & 15;

  // ---- stage weights as fp16 W^T (k-permutation F for layers 1..9), bias
  //      at the slot mapping to k==KL; 44 rows per slot ----
  {
    const float* Wp[10] = {W0, W1, W2, W3, W4, W5, W6, W7, W8, W9};
    const float* Bp[10] = {B0, B1, B2, B3, B4, B5, B6, B7, B8, B9};
    const int KLs[10] = {43, 43, 43, 43, 43, 21, 43, 43, 43, 43};
    const int NLs[10] = {43, 43, 43, 43, 21, 43, 43, 43, 43, 43};
#pragma unroll
    for (int L = 0; L < 10; ++L) {
      const float* Wl = Wp[L];
      const float* Bl = Bp[L];
      const int KL = KLs[L], NL = NLs[L];
      for (int idx = tid; idx < SLOT_ROWS * 64; idx += TPB) {
        int n = idx >> 6, kp = idx & 63;
        float v = 0.0f;
        if (n < NL) {
          int c = kp >> 5, g2 = (kp >> 3) & 3, j = kp & 7;
          int F;
          if (L == 0) F = kp;                               // natural
          else if (c == 0) F = 16 * (j >> 2) + 4 * g2 + (j & 3);
          else if (j < 4)  F = 32 + 4 * g2 + j;             // t=2 half
          else             F = 63;                          // zero pad slot
          if (F < KL) v = Wl[F * NL + n];                   // W^T: W[F][n]
          else if (F == KL) v = Bl[n];                      // bias row
        }
        lw[L * WSLOT + n * WSTRIDE + kp] = (_Float16)v;
      }
    }
  }

  // per-lane DMA source offsets: LDS quad u=64i+lane holds x bytes
  // [r*172 + q*16) with r=u/11, q=u%11  (LDS layout = [32 rows][176 B])
  unsigned dmaoff[6];
#pragma unroll
  for (int i = 0; i < 6; ++i) {
    unsigned u = 64u * i + (unsigned)lane;
    dmaoff[i] = (u / 11u) * ROWB + (u % 11u) * 16u;
  }

  __syncthreads();  // weights ready; only barrier in the kernel

  const char* xc = (const char*)x;
  const char* xlim = xc + (XBYTES - 16);
  const unsigned blockbase = (unsigned)blockIdx.x * (ITERS * 512) + wave * 32;
  float* xb = (float*)(smem + X_BASE + wave * XBUF_BYTES);
  const f32x4 Z = {0.f, 0.f, 0.f, 0.f};   // shared MFMA C-init block

  // issue DMA of tile 0
  {
    const char* base = xc + blockbase * ROWB;
#pragma unroll
    for (int i = 0; i < 6; ++i) {
      const char* src = base + dmaoff[i];
      src = (src > xlim) ? xlim : src;
      __builtin_amdgcn_global_load_lds(
          (const __attribute__((address_space(1))) void*)src,
          (__attribute__((address_space(3))) void*)((char*)xb + i * 1024),
          16, 0, 0);
    }
  }

  A6 a0c = load_A<3, 2>(lw + 0 * WSLOT, g, lr);   // layer-0 A, loop-carried

#pragma unroll 1
  for (int it = 0; it < ITERS; ++it) {
    const unsigned row0 = blockbase + (unsigned)it * 512u;

    asm volatile("s_waitcnt vmcnt(0)" ::: "memory");  // x tile landed in LDS

    // ---- layer-0 B-frags from aligned LDS rows; slot k==43 := 1.0 ----
    FragsV B;
#pragma unroll
    for (int s = 0; s < 2; ++s) {
      const float* xr = xb + (16 * s + lr) * XROWF;
      f32x4 q0 = *(const f32x4*)(xr + 8 * g);
      f32x4 q1 = *(const f32x4*)(xr + 8 * g + 4);
      f32x4 q2 = *(const f32x4*)(xr + 32 + 8 * g);   // g>=2 bleeds into next
      f32x4 q3 = *(const f32x4*)(xr + 36 + 8 * g);   // row: junk, annihilated
      float e3 = (g == 1) ? 1.0f : q2[3];            // k==43 bias multiplier
      u32x4 d0 = {pk2(q0[0], q0[1]), pk2(q0[2], q0[3]),
                  pk2(q1[0], q1[1]), pk2(q1[2], q1[3])};
      u32x4 d1 = {pk2(q2[0], q2[1]), pk2(q2[2], e3),
                  pk2(q3[0], q3[1]), pk2(q3[2], q3[3])};
      if (s == 0) { B.s0c0 = __builtin_bit_cast(f16x8, d0);
                    B.s0c1 = __builtin_bit_cast(f16x8, d1); }
      else        { B.s1c0 = __builtin_bit_cast(f16x8, d0);
                    B.s1c1 = __builtin_bit_cast(f16x8, d1); }
    }

    // frag reads complete -> safe to overwrite the buffer with next tile
    asm volatile("s_waitcnt lgkmcnt(0)" ::: "memory");
    if (it + 1 < ITERS) {
      const char* base = xc + (row0 + 512u) * ROWB;
#pragma unroll
      for (int i = 0; i < 6; ++i) {
        const char* src = base + dmaoff[i];
        src = (src > xlim) ? xlim : src;
        __builtin_amdgcn_global_load_lds(
            (const __attribute__((address_space(1))) void*)src,
            (__attribute__((address_space(3))) void*)((char*)xb + i * 1024),
            16, 0, 0);
      }
    }

    // ---- layers 0..8: prefetch next layer's A, then compute current ----
    A6 a1v = load_A<3, 2>(lw + 1 * WSLOT, g, lr);
    B = layer_fwd<3, 2, true, 43, 2>(a0c, B, Z, g);
    A6 a2v = load_A<3, 2>(lw + 2 * WSLOT, g, lr);
    B = layer_fwd<3, 2, true, 43, 2>(a1v, B, Z, g);
    A6 a3v = load_A<3, 2>(lw + 3 * WSLOT, g, lr);
    B = layer_fwd<3, 2, true, 43, 2>(a2v, B, Z, g);
    A6 a4v = load_A<2, 2>(lw + 4 * WSLOT, g, lr);
    B = layer_fwd<3, 2, true, 43, 2>(a3v, B, Z, g);
    A6 a5v = load_A<3, 1>(lw + 5 * WSLOT, g, lr);
    B = layer_fwd<2, 2, false, 21, 1>(a4v, B, Z, g);  // bottleneck (linear)
    A6 a6v = load_A<3, 2>(lw + 6 * WSLOT, g, lr);
    B = layer_fwd<3, 1, true, 43, 2>(a5v, B, Z, g);   // K=21 -> 1 chunk
    A6 a7v = load_A<3, 2>(lw + 7 * WSLOT, g, lr);
    B = layer_fwd<3, 2, true, 43, 2>(a6v, B, Z, g);
    A6 a8v = load_A<3, 2>(lw + 8 * WSLOT, g, lr);
    B = layer_fwd<3, 2, true, 43, 2>(a7v, B, Z, g);
    A6 a9v = load_A<3, 2>(lw + 9 * WSLOT, g, lr);
    B = layer_fwd<3, 2, true, 43, 2>(a8v, B, Z, g);

    a0c = load_A<3, 2>(lw + 0 * WSLOT, g, lr);        // next iter's layer-0 A

    // ---- layer 9: linear, store fp32 via base + immediate offsets ----
    {
      f16x8 Bv0[2] = {B.s0c0, B.s1c0};
      f16x8 Bv1[2] = {B.s0c1, B.s1c1};
      f32x4 a9[3][2];
#pragma unroll
      for (int s = 0; s < 2; ++s) {
        a9[0][s] = __builtin_amdgcn_mfma_f32_16x16x32_f16(a9v.m0, Bv0[s], Z,
                                                          0, 0, 0);
        a9[1][s] = __builtin_amdgcn_mfma_f32_16x16x32_f16(a9v.m1, Bv0[s], Z,
                                                          0, 0, 0);
        a9[2][s] = __builtin_amdgcn_mfma_f32_16x16x32_f16(a9v.m2, Bv0[s], Z,
                                                          0, 0, 0);
        a9[0][s] = __builtin_amdgcn_mfma_f32_16x16x32_f16(a9v.m3, Bv1[s],
                                                          a9[0][s], 0, 0, 0);
        a9[1][s] = __builtin_amdgcn_mfma_f32_16x16x32_f16(a9v.m4, Bv1[s],
                                                          a9[1][s], 0, 0, 0);
        a9[2][s] = __builtin_amdgcn_mfma_f32_16x16x32_f16(a9v.m5, Bv1[s],
                                                          a9[2][s], 0, 0, 0);
      }
      char* ob = (char*)out + ((size_t)(row0 + lr) * ROWB + 16u * g);
#pragma unroll
      for (int t = 0; t < 3; ++t)
#pragma unroll
        for (int s = 0; s < 2; ++s)
#pragma unroll
          for (int r = 0; r < 4; ++r) {
            // col = 16t + 4g + r < 43; t<2 always in range
            if (t < 2 || 4 * g + r < 11)
              *(float*)(ob + 2752 * s + 64 * t + 4 * r) = a9[t][s][r];
          }
    }
  }
}

extern "C" void kernel_launch(void* const* d_in, const int* in_sizes, int n_in,
                              void* d_out, int out_size, void* d_ws,
                              size_t ws_size, hipStream_t stream) {
  const float* x = (const float*)d_in[0];
  const float* W[10];
  const float* B[10];
  for (int i = 0; i < 10; ++i) {
    W[i] = (const float*)d_in[1 + 2 * i];
    B[i] = (const float*)d_in[2 + 2 * i];
  }
  (void)hipFuncSetAttribute(reinterpret_cast<const void*>(ae_kernel),
                            hipFuncAttributeMaxDynamicSharedMemorySize,
                            SMEM_BYTES);
  ae_kernel<<<dim3(NBLK), dim3(TPB), SMEM_BYTES, stream>>>(
      x, W[0], B[0], W[1], B[1], W[2], B[2], W[3], B[3], W[4], B[4],
      W[5], B[5], W[6], B[6], W[7], B[7], W[8], B[8], W[9], B[9],
      (float*)d_out);
}